// Round 2
// baseline (4669.075 us; speedup 1.0000x reference)
//
#include <hip/hip_runtime.h>
#include <hip/hip_bf16.h>

#define D_   64
#define L_   6
#define B_   4
#define K_   256
#define NN   20000
#define EE   200000
#define RR   200
#define ER_  4000
#define EPS_ 1e-5f

// ---------------- rel-graph init: x = boundary (1.0 at r_index row), agg = 0
__global__ __launch_bounds__(256)
void k_rel_init(float* __restrict__ x, float* __restrict__ agg, const int* __restrict__ batch) {
    int idx = blockIdx.x * 256 + threadIdx.x;              // over B*RR*16 float4
    int total = B_ * RR * (D_ / 4);
    if (idx >= total) return;
    int r = (idx >> 4) % RR;
    int b = (idx >> 4) / RR;
    int ridx = batch[b * K_ * 3 + 2];
    float4 v = make_float4(0.f, 0.f, 0.f, 0.f);
    if (r == ridx) v = make_float4(1.f, 1.f, 1.f, 1.f);
    reinterpret_cast<float4*>(x)[idx] = v;
    reinterpret_cast<float4*>(agg)[idx] = make_float4(0.f, 0.f, 0.f, 0.f);
}

// ---------------- rel-graph edge scatter: agg[dst] += x[src] * rel_emb[et]
__global__ __launch_bounds__(256)
void k_rel_scatter(const float* __restrict__ x, const float* __restrict__ rel_emb,
                   const int* __restrict__ ei, const int* __restrict__ et,
                   float* __restrict__ agg) {
    int gtid = blockIdx.x * 256 + threadIdx.x;
    int e = gtid >> 6;
    if (e >= ER_) return;
    int sub = gtid & 63;
    int b  = sub >> 4;
    int d4 = sub & 15;
    int src = ei[e];
    int dst = ei[ER_ + e];
    int t   = et[e];
    float4 xv = reinterpret_cast<const float4*>(x)[(b * RR + src) * 16 + d4];
    float4 rv = reinterpret_cast<const float4*>(rel_emb)[t * 16 + d4];
    float* p = agg + (b * RR + dst) * 64 + d4 * 4;
    atomicAdd(p + 0, xv.x * rv.x);
    atomicAdd(p + 1, xv.y * rv.y);
    atomicAdd(p + 2, xv.z * rv.z);
    atomicAdd(p + 3, xv.w * rv.w);
}

// ---------------- ent-graph edge scatter: agg[b,dst] += x[b,src] * rel[b,et]
__global__ __launch_bounds__(256)
void k_ent_scatter(const float* __restrict__ x, const float* __restrict__ rel,
                   const int* __restrict__ ei, const int* __restrict__ et,
                   float* __restrict__ agg) {
    int gtid = blockIdx.x * 256 + threadIdx.x;
    int e = gtid >> 6;
    if (e >= EE) return;
    int sub = gtid & 63;
    int b  = sub >> 4;
    int d4 = sub & 15;
    int src = ei[e];
    int dst = ei[EE + e];
    int t   = et[e];
    float4 xv = reinterpret_cast<const float4*>(x)[(b * NN + src) * 16 + d4];
    float4 rv = reinterpret_cast<const float4*>(rel)[(b * RR + t) * 16 + d4];
    float* p = agg + (size_t)(b * NN + dst) * 64 + d4 * 4;
    atomicAdd(p + 0, xv.x * rv.x);
    atomicAdd(p + 1, xv.y * rv.y);
    atomicAdd(p + 2, xv.z * rv.z);
    atomicAdd(p + 3, xv.w * rv.w);
}

// ---------------- conv GEMM + LN + relu + residual; re-zeroes agg for next layer
// rows = B*NNODES, in = concat(x, agg + boundary), out: x += relu(LN(in @ W + b))
// MODE 0: rel graph (boundary = 1.0 at r_index). MODE 1: ent graph (boundary = query at h_index).
template<int NNODES, int MODE>
__global__ __launch_bounds__(256)
void k_conv(float* __restrict__ x, float* __restrict__ agg,
            const float* __restrict__ query,
            const float* __restrict__ W, const float* __restrict__ bias,
            const float* __restrict__ g, const float* __restrict__ bt,
            const int* __restrict__ batch) {
    __shared__ float As[128][68];     // [k][m], padded
    __shared__ float Bs[128][64];     // W tile
    __shared__ int   bnode_s[B_];
    const int tid = threadIdx.x;
    const int row0 = blockIdx.x * 64;
    const int total_rows = B_ * NNODES;

    if (tid < B_) bnode_s[tid] = batch[tid * K_ * 3 + (MODE ? 0 : 2)];

    // stage W
    {
        const float4* W4 = reinterpret_cast<const float4*>(W);
        float4* Bs4 = reinterpret_cast<float4*>(&Bs[0][0]);
        for (int i = tid; i < 2048; i += 256) Bs4[i] = W4[i];
    }
    __syncthreads();

    // stage A: As[k][m] = concat(x,agg+boundary)[row0+m][k]
    for (int idx = tid; idx < 64 * 128; idx += 256) {
        int m = idx >> 7;
        int k = idx & 127;
        int row = row0 + m;
        float v = 0.f;
        if (row < total_rows) {
            int b = row / NNODES;
            int n = row - b * NNODES;
            if (k < 64) {
                v = x[row * 64 + k];
            } else {
                int kk = k - 64;
                v = agg[row * 64 + kk];
                if (n == bnode_s[b]) v += MODE ? query[b * 64 + kk] : 1.0f;
            }
        }
        As[k][m] = v;
    }
    __syncthreads();

    const int tx = tid & 15;   // output col group (4 cols)
    const int ty = tid >> 4;   // row group (4 rows)
    float acc[4][4];
    #pragma unroll
    for (int j = 0; j < 4; j++)
        #pragma unroll
        for (int i = 0; i < 4; i++) acc[j][i] = 0.f;

    #pragma unroll 4
    for (int k = 0; k < 128; ++k) {
        float4 a = *reinterpret_cast<const float4*>(&As[k][ty * 4]);
        float4 w = *reinterpret_cast<const float4*>(&Bs[k][tx * 4]);
        float av[4] = {a.x, a.y, a.z, a.w};
        float bv[4] = {w.x, w.y, w.z, w.w};
        #pragma unroll
        for (int j = 0; j < 4; j++)
            #pragma unroll
            for (int i = 0; i < 4; i++)
                acc[j][i] = fmaf(av[j], bv[i], acc[j][i]);
    }

    float bb[4], gg[4], bbt[4];
    #pragma unroll
    for (int i = 0; i < 4; i++) {
        bb[i]  = bias[tx * 4 + i];
        gg[i]  = g[tx * 4 + i];
        bbt[i] = bt[tx * 4 + i];
    }

    #pragma unroll
    for (int j = 0; j < 4; j++) {
        int row = row0 + ty * 4 + j;
        float o[4];
        float s1 = 0.f, s2 = 0.f;
        #pragma unroll
        for (int i = 0; i < 4; i++) {
            o[i] = acc[j][i] + bb[i];
            s1 += o[i];
            s2 += o[i] * o[i];
        }
        #pragma unroll
        for (int off = 1; off < 16; off <<= 1) {
            s1 += __shfl_xor(s1, off);
            s2 += __shfl_xor(s2, off);
        }
        float mean = s1 * (1.f / 64.f);
        float var  = s2 * (1.f / 64.f) - mean * mean;
        float inv  = rsqrtf(var + EPS_);
        if (row < total_rows) {
            float nv[4];
            #pragma unroll
            for (int i = 0; i < 4; i++) {
                float h = (o[i] - mean) * inv * gg[i] + bbt[i];
                h = fmaxf(h, 0.f);
                nv[i] = As[tx * 4 + i][ty * 4 + j] + h;   // residual: x_old
            }
            *reinterpret_cast<float4*>(&x[row * 64 + tx * 4]) =
                make_float4(nv[0], nv[1], nv[2], nv[3]);
            *reinterpret_cast<float4*>(&agg[row * 64 + tx * 4]) =
                make_float4(0.f, 0.f, 0.f, 0.f);          // zero for next layer
        }
    }
}

// ---------------- per-layer relation MLP: out = relu(rel_repr@Wp1+bp1)@Wp2+bp2
__global__ __launch_bounds__(64)
void k_rel_mlp(const float* __restrict__ rel_repr,
               const float* __restrict__ Wp1, const float* __restrict__ bp1,
               const float* __restrict__ Wp2, const float* __restrict__ bp2,
               float* __restrict__ out) {
    __shared__ float rowv[64];
    __shared__ float hid[64];
    int rowid = blockIdx.x;
    int d = threadIdx.x;
    rowv[d] = rel_repr[rowid * 64 + d];
    __syncthreads();
    float acc = bp1[d];
    for (int k = 0; k < 64; k++) acc = fmaf(rowv[k], Wp1[k * 64 + d], acc);
    hid[d] = fmaxf(acc, 0.f);
    __syncthreads();
    float o = bp2[d];
    for (int k = 0; k < 64; k++) o = fmaf(hid[k], Wp2[k * 64 + d], o);
    out[rowid * 64 + d] = o;
}

// ---------------- query[b] = rel_repr[b, r_index[b]]
__global__ __launch_bounds__(256)
void k_query(const float* __restrict__ rel_repr, const int* __restrict__ batch,
             float* __restrict__ query) {
    int tid = threadIdx.x;  // 256 = B*64
    int b = tid >> 6;
    int d = tid & 63;
    int r = batch[b * K_ * 3 + 2];
    query[b * 64 + d] = rel_repr[(b * RR + r) * 64 + d];
}

// ---------------- ent init: x = boundary (query at h_index row), agg = 0
__global__ __launch_bounds__(256)
void k_ent_init(float* __restrict__ x, float* __restrict__ agg,
                const float* __restrict__ query, const int* __restrict__ batch) {
    int idx = blockIdx.x * 256 + threadIdx.x;  // over B*NN*16 float4
    int total = B_ * NN * (D_ / 4);
    if (idx >= total) return;
    int d4 = idx & 15;
    int rest = idx >> 4;
    int n = rest % NN;
    int b = rest / NN;
    int h = batch[b * K_ * 3];
    float4 v = make_float4(0.f, 0.f, 0.f, 0.f);
    if (n == h) v = reinterpret_cast<const float4*>(query)[b * 16 + d4];
    reinterpret_cast<float4*>(x)[idx] = v;
    reinterpret_cast<float4*>(agg)[idx] = make_float4(0.f, 0.f, 0.f, 0.f);
}

// ---------------- final MLP over gathered rows
__global__ __launch_bounds__(128)
void k_final(const float* __restrict__ x, const float* __restrict__ query,
             const int* __restrict__ batch,
             const float* __restrict__ W1, const float* __restrict__ b1,
             const float* __restrict__ W2, const float* __restrict__ b2,
             float* __restrict__ out) {
    __shared__ float feat[128];
    __shared__ float partial[2];
    int pair = blockIdx.x;          // b*K + k
    int b = pair / K_;
    int t = batch[pair * 3 + 1];
    int d = threadIdx.x;
    feat[d] = (d < 64) ? x[(size_t)(b * NN + t) * 64 + d] : query[b * 64 + (d - 64)];
    __syncthreads();
    float h = b1[d];
    for (int i = 0; i < 128; i++) h = fmaf(feat[i], W1[i * 128 + d], h);
    h = fmaxf(h, 0.f);
    float v = h * W2[d];
    #pragma unroll
    for (int off = 1; off < 64; off <<= 1) v += __shfl_xor(v, off);
    if ((d & 63) == 0) partial[d >> 6] = v;
    __syncthreads();
    if (d == 0) out[pair] = partial[0] + partial[1] + b2[0];
}

extern "C" void kernel_launch(void* const* d_in, const int* in_sizes, int n_in,
                              void* d_out, int out_size, void* d_ws, size_t ws_size,
                              hipStream_t stream) {
    const int* batch      = (const int*)d_in[0];
    const int* edge_index = (const int*)d_in[1];
    const int* edge_type  = (const int*)d_in[2];
    const int* rel_ei     = (const int*)d_in[3];
    const int* rel_et     = (const int*)d_in[4];
    const float* rel_emb = (const float*)d_in[7];
    const float* Wr  = (const float*)d_in[8];
    const float* br  = (const float*)d_in[9];
    const float* gr  = (const float*)d_in[10];
    const float* btr = (const float*)d_in[11];
    const float* Wp1 = (const float*)d_in[12];
    const float* bp1 = (const float*)d_in[13];
    const float* Wp2 = (const float*)d_in[14];
    const float* bp2 = (const float*)d_in[15];
    const float* We  = (const float*)d_in[16];
    const float* be  = (const float*)d_in[17];
    const float* ge  = (const float*)d_in[18];
    const float* bte = (const float*)d_in[19];
    const float* W1  = (const float*)d_in[20];
    const float* b1  = (const float*)d_in[21];
    const float* W2  = (const float*)d_in[22];
    const float* b2  = (const float*)d_in[23];

    float* ws        = (float*)d_ws;
    float* rel_repr  = ws;                       // B*RR*64 = 51200
    float* rel_agg   = ws + 51200;               // 51200
    float* rel_layer = ws + 102400;              // 51200
    float* query     = ws + 153600;              // 256
    float* x_ent     = ws + 153856;              // B*NN*64 = 5,120,000
    float* agg_ent   = x_ent + (size_t)B_ * NN * 64;

    // ---- relation-graph model ----
    k_rel_init<<<(B_ * RR * 16 + 255) / 256, 256, 0, stream>>>(rel_repr, rel_agg, batch);
    for (int l = 0; l < L_; ++l) {
        k_rel_scatter<<<ER_ * 64 / 256, 256, 0, stream>>>(rel_repr, rel_emb, rel_ei, rel_et, rel_agg);
        k_conv<RR, 0><<<(B_ * RR + 63) / 64, 256, 0, stream>>>(
            rel_repr, rel_agg, nullptr,
            Wr + l * 8192, br + l * 64, gr + l * 64, btr + l * 64, batch);
    }

    // ---- entity-graph model ----
    k_query<<<1, 256, 0, stream>>>(rel_repr, batch, query);
    k_ent_init<<<B_ * NN * 16 / 256, 256, 0, stream>>>(x_ent, agg_ent, query, batch);
    for (int l = 0; l < L_; ++l) {
        k_rel_mlp<<<B_ * RR, 64, 0, stream>>>(rel_repr,
            Wp1 + l * 4096, bp1 + l * 64, Wp2 + l * 4096, bp2 + l * 64, rel_layer);
        k_ent_scatter<<<EE * 64 / 256, 256, 0, stream>>>(x_ent, rel_layer, edge_index, edge_type, agg_ent);
        k_conv<NN, 1><<<(B_ * NN + 63) / 64, 256, 0, stream>>>(
            x_ent, agg_ent, query,
            We + l * 8192, be + l * 64, ge + l * 64, bte + l * 64, batch);
    }
    k_final<<<B_ * K_, 128, 0, stream>>>(x_ent, query, batch, W1, b1, W2, b2,
                                         (float*)d_out);
}

// Round 3
// 824.419 us; speedup vs baseline: 5.6635x; 5.6635x over previous
//
#include <hip/hip_runtime.h>
#include <hip/hip_bf16.h>

#define D_   64
#define L_   6
#define B_   4
#define K_   256
#define NN   20000
#define EE   200000
#define RR   200
#define ER_  4000
#define EPS_ 1e-5f

// ================= CSR build (generic, run once per launch per graph) =======
__global__ __launch_bounds__(256)
void k_zero_int(int* __restrict__ p, int n) {
    int i = blockIdx.x * 256 + threadIdx.x;
    if (i < n) p[i] = 0;
}

__global__ __launch_bounds__(256)
void k_hist(const int* __restrict__ ei, int E, int* __restrict__ counts) {
    int e = blockIdx.x * 256 + threadIdx.x;
    if (e < E) atomicAdd(&counts[ei[E + e]], 1);
}

// single-block scan: row_ptr[0..n] = exclusive prefix of counts; counts becomes cursor copy
__global__ __launch_bounds__(256)
void k_scan(int* __restrict__ counts, int* __restrict__ row_ptr, int n) {
    __shared__ int sums[256];
    int tid = threadIdx.x;
    int chunk = (n + 255) / 256;
    int lo = tid * chunk;
    int hi = lo + chunk; if (hi > n) hi = n;
    if (lo > n) lo = n;
    int s = 0;
    for (int i = lo; i < hi; i++) s += counts[i];
    sums[tid] = s;
    __syncthreads();
    if (tid == 0) {
        int acc = 0;
        for (int i = 0; i < 256; i++) { int t = sums[i]; sums[i] = acc; acc += t; }
    }
    __syncthreads();
    int run = sums[tid];
    for (int i = lo; i < hi; i++) {
        int c = counts[i];
        row_ptr[i] = run;
        counts[i] = run;        // cursor init (reuse counts buffer)
        run += c;
    }
    if (hi == n) row_ptr[n] = run;   // trailing threads write total (same value)
}

__global__ __launch_bounds__(256)
void k_fill(const int* __restrict__ ei, const int* __restrict__ et, int E,
            int* __restrict__ cursor, int* __restrict__ packed) {
    int e = blockIdx.x * 256 + threadIdx.x;
    if (e < E) {
        int pos = atomicAdd(&cursor[ei[E + e]], 1);
        packed[pos] = ei[e] | (et[e] << 15);     // src < 32768, et < 200
    }
}

// ================= rel-graph init: x = boundary (1.0 at r_index row) ========
__global__ __launch_bounds__(256)
void k_rel_init(float* __restrict__ x, const int* __restrict__ batch) {
    int idx = blockIdx.x * 256 + threadIdx.x;              // over B*RR*16 float4
    int total = B_ * RR * (D_ / 4);
    if (idx >= total) return;
    int r = (idx >> 4) % RR;
    int b = (idx >> 4) / RR;
    int ridx = batch[b * K_ * 3 + 2];
    float4 v = make_float4(0.f, 0.f, 0.f, 0.f);
    if (r == ridx) v = make_float4(1.f, 1.f, 1.f, 1.f);
    reinterpret_cast<float4*>(x)[idx] = v;
}

// ================= CSR aggregation: agg[b,n] = boundary + sum_in x[b,src]*rel[et]
// one wave per node, lane = dim, all B batches in registers
__global__ __launch_bounds__(256)
void k_agg_rel(const float* __restrict__ x, const float* __restrict__ rel_emb,
               const int* __restrict__ row_ptr, const int* __restrict__ packed,
               const int* __restrict__ batch, float* __restrict__ agg) {
    int node = blockIdx.x * 4 + (threadIdx.x >> 6);
    int d = threadIdx.x & 63;
    if (node >= RR) return;
    int beg = row_ptr[node], end = row_ptr[node + 1];
    float a0 = 0.f, a1 = 0.f, a2 = 0.f, a3 = 0.f;
    for (int e = beg; e < end; e++) {
        int p = packed[e];
        int src = p & 0x7FFF;
        int et  = p >> 15;
        float rv = rel_emb[et * 64 + d];
        a0 = fmaf(x[(0 * RR + src) * 64 + d], rv, a0);
        a1 = fmaf(x[(1 * RR + src) * 64 + d], rv, a1);
        a2 = fmaf(x[(2 * RR + src) * 64 + d], rv, a2);
        a3 = fmaf(x[(3 * RR + src) * 64 + d], rv, a3);
    }
    if (node == batch[0 * K_ * 3 + 2]) a0 += 1.f;
    if (node == batch[1 * K_ * 3 + 2]) a1 += 1.f;
    if (node == batch[2 * K_ * 3 + 2]) a2 += 1.f;
    if (node == batch[3 * K_ * 3 + 2]) a3 += 1.f;
    agg[(0 * RR + node) * 64 + d] = a0;
    agg[(1 * RR + node) * 64 + d] = a1;
    agg[(2 * RR + node) * 64 + d] = a2;
    agg[(3 * RR + node) * 64 + d] = a3;
}

__global__ __launch_bounds__(256)
void k_agg_ent(const float* __restrict__ x, const float* __restrict__ rel,
               const int* __restrict__ row_ptr, const int* __restrict__ packed,
               const float* __restrict__ query, const int* __restrict__ batch,
               float* __restrict__ agg) {
    int node = blockIdx.x * 4 + (threadIdx.x >> 6);
    int d = threadIdx.x & 63;
    if (node >= NN) return;
    int beg = row_ptr[node], end = row_ptr[node + 1];
    float a0 = 0.f, a1 = 0.f, a2 = 0.f, a3 = 0.f;
    for (int e = beg; e < end; e++) {
        int p = packed[e];
        int src = p & 0x7FFF;
        int et  = p >> 15;
        a0 = fmaf(x[((size_t)0 * NN + src) * 64 + d], rel[(0 * RR + et) * 64 + d], a0);
        a1 = fmaf(x[((size_t)1 * NN + src) * 64 + d], rel[(1 * RR + et) * 64 + d], a1);
        a2 = fmaf(x[((size_t)2 * NN + src) * 64 + d], rel[(2 * RR + et) * 64 + d], a2);
        a3 = fmaf(x[((size_t)3 * NN + src) * 64 + d], rel[(3 * RR + et) * 64 + d], a3);
    }
    if (node == batch[0 * K_ * 3]) a0 += query[0 * 64 + d];
    if (node == batch[1 * K_ * 3]) a1 += query[1 * 64 + d];
    if (node == batch[2 * K_ * 3]) a2 += query[2 * 64 + d];
    if (node == batch[3 * K_ * 3]) a3 += query[3 * 64 + d];
    agg[((size_t)0 * NN + node) * 64 + d] = a0;
    agg[((size_t)1 * NN + node) * 64 + d] = a1;
    agg[((size_t)2 * NN + node) * 64 + d] = a2;
    agg[((size_t)3 * NN + node) * 64 + d] = a3;
}

// ================= conv GEMM + LN + relu + residual ========================
// rows = B*NNODES, in = concat(x, agg), x += relu(LN(in @ W + b))
template<int NNODES>
__global__ __launch_bounds__(256)
void k_conv(float* __restrict__ x, const float* __restrict__ agg,
            const float* __restrict__ W, const float* __restrict__ bias,
            const float* __restrict__ g, const float* __restrict__ bt) {
    __shared__ float As[128][68];     // [k][m], padded
    __shared__ float Bs[128][64];     // W tile
    const int tid = threadIdx.x;
    const int row0 = blockIdx.x * 64;
    const int total_rows = B_ * NNODES;

    // stage W
    {
        const float4* W4 = reinterpret_cast<const float4*>(W);
        float4* Bs4 = reinterpret_cast<float4*>(&Bs[0][0]);
        for (int i = tid; i < 2048; i += 256) Bs4[i] = W4[i];
    }

    // stage A: As[k][m] = concat(x,agg)[row0+m][k]
    for (int idx = tid; idx < 64 * 128; idx += 256) {
        int m = idx >> 7;
        int k = idx & 127;
        int row = row0 + m;
        float v = 0.f;
        if (row < total_rows)
            v = (k < 64) ? x[(size_t)row * 64 + k] : agg[(size_t)row * 64 + (k - 64)];
        As[k][m] = v;
    }
    __syncthreads();

    const int tx = tid & 15;   // output col group (4 cols)
    const int ty = tid >> 4;   // row group (4 rows)
    float acc[4][4];
    #pragma unroll
    for (int j = 0; j < 4; j++)
        #pragma unroll
        for (int i = 0; i < 4; i++) acc[j][i] = 0.f;

    #pragma unroll 4
    for (int k = 0; k < 128; ++k) {
        float4 a = *reinterpret_cast<const float4*>(&As[k][ty * 4]);
        float4 w = *reinterpret_cast<const float4*>(&Bs[k][tx * 4]);
        float av[4] = {a.x, a.y, a.z, a.w};
        float bv[4] = {w.x, w.y, w.z, w.w};
        #pragma unroll
        for (int j = 0; j < 4; j++)
            #pragma unroll
            for (int i = 0; i < 4; i++)
                acc[j][i] = fmaf(av[j], bv[i], acc[j][i]);
    }

    float bb[4], gg[4], bbt[4];
    #pragma unroll
    for (int i = 0; i < 4; i++) {
        bb[i]  = bias[tx * 4 + i];
        gg[i]  = g[tx * 4 + i];
        bbt[i] = bt[tx * 4 + i];
    }

    #pragma unroll
    for (int j = 0; j < 4; j++) {
        int row = row0 + ty * 4 + j;
        float o[4];
        float s1 = 0.f, s2 = 0.f;
        #pragma unroll
        for (int i = 0; i < 4; i++) {
            o[i] = acc[j][i] + bb[i];
            s1 += o[i];
            s2 += o[i] * o[i];
        }
        #pragma unroll
        for (int off = 1; off < 16; off <<= 1) {
            s1 += __shfl_xor(s1, off);
            s2 += __shfl_xor(s2, off);
        }
        float mean = s1 * (1.f / 64.f);
        float var  = s2 * (1.f / 64.f) - mean * mean;
        float inv  = rsqrtf(var + EPS_);
        if (row < total_rows) {
            float nv[4];
            #pragma unroll
            for (int i = 0; i < 4; i++) {
                float h = (o[i] - mean) * inv * gg[i] + bbt[i];
                h = fmaxf(h, 0.f);
                nv[i] = As[tx * 4 + i][ty * 4 + j] + h;   // residual: x_old
            }
            *reinterpret_cast<float4*>(&x[(size_t)row * 64 + tx * 4]) =
                make_float4(nv[0], nv[1], nv[2], nv[3]);
        }
    }
}

// ================= per-layer relation MLP ==================================
__global__ __launch_bounds__(64)
void k_rel_mlp(const float* __restrict__ rel_repr,
               const float* __restrict__ Wp1, const float* __restrict__ bp1,
               const float* __restrict__ Wp2, const float* __restrict__ bp2,
               float* __restrict__ out) {
    __shared__ float rowv[64];
    __shared__ float hid[64];
    int rowid = blockIdx.x;
    int d = threadIdx.x;
    rowv[d] = rel_repr[rowid * 64 + d];
    __syncthreads();
    float acc = bp1[d];
    for (int k = 0; k < 64; k++) acc = fmaf(rowv[k], Wp1[k * 64 + d], acc);
    hid[d] = fmaxf(acc, 0.f);
    __syncthreads();
    float o = bp2[d];
    for (int k = 0; k < 64; k++) o = fmaf(hid[k], Wp2[k * 64 + d], o);
    out[rowid * 64 + d] = o;
}

// ================= query[b] = rel_repr[b, r_index[b]] ======================
__global__ __launch_bounds__(256)
void k_query(const float* __restrict__ rel_repr, const int* __restrict__ batch,
             float* __restrict__ query) {
    int tid = threadIdx.x;  // 256 = B*64
    int b = tid >> 6;
    int d = tid & 63;
    int r = batch[b * K_ * 3 + 2];
    query[b * 64 + d] = rel_repr[(b * RR + r) * 64 + d];
}

// ================= ent init: x = boundary (query at h_index row) ===========
__global__ __launch_bounds__(256)
void k_ent_init(float* __restrict__ x, const float* __restrict__ query,
                const int* __restrict__ batch) {
    int idx = blockIdx.x * 256 + threadIdx.x;  // over B*NN*16 float4
    int total = B_ * NN * (D_ / 4);
    if (idx >= total) return;
    int d4 = idx & 15;
    int rest = idx >> 4;
    int n = rest % NN;
    int b = rest / NN;
    int h = batch[b * K_ * 3];
    float4 v = make_float4(0.f, 0.f, 0.f, 0.f);
    if (n == h) v = reinterpret_cast<const float4*>(query)[b * 16 + d4];
    reinterpret_cast<float4*>(x)[idx] = v;
}

// ================= final MLP over gathered rows ============================
__global__ __launch_bounds__(128)
void k_final(const float* __restrict__ x, const float* __restrict__ query,
             const int* __restrict__ batch,
             const float* __restrict__ W1, const float* __restrict__ b1,
             const float* __restrict__ W2, const float* __restrict__ b2,
             float* __restrict__ out) {
    __shared__ float feat[128];
    __shared__ float partial[2];
    int pair = blockIdx.x;          // b*K + k
    int b = pair / K_;
    int t = batch[pair * 3 + 1];
    int d = threadIdx.x;
    feat[d] = (d < 64) ? x[(size_t)(b * NN + t) * 64 + d] : query[b * 64 + (d - 64)];
    __syncthreads();
    float h = b1[d];
    for (int i = 0; i < 128; i++) h = fmaf(feat[i], W1[i * 128 + d], h);
    h = fmaxf(h, 0.f);
    float v = h * W2[d];
    #pragma unroll
    for (int off = 1; off < 64; off <<= 1) v += __shfl_xor(v, off);
    if ((d & 63) == 0) partial[d >> 6] = v;
    __syncthreads();
    if (d == 0) out[pair] = partial[0] + partial[1] + b2[0];
}

extern "C" void kernel_launch(void* const* d_in, const int* in_sizes, int n_in,
                              void* d_out, int out_size, void* d_ws, size_t ws_size,
                              hipStream_t stream) {
    const int* batch      = (const int*)d_in[0];
    const int* edge_index = (const int*)d_in[1];
    const int* edge_type  = (const int*)d_in[2];
    const int* rel_ei     = (const int*)d_in[3];
    const int* rel_et     = (const int*)d_in[4];
    const float* rel_emb = (const float*)d_in[7];
    const float* Wr  = (const float*)d_in[8];
    const float* br  = (const float*)d_in[9];
    const float* gr  = (const float*)d_in[10];
    const float* btr = (const float*)d_in[11];
    const float* Wp1 = (const float*)d_in[12];
    const float* bp1 = (const float*)d_in[13];
    const float* Wp2 = (const float*)d_in[14];
    const float* bp2 = (const float*)d_in[15];
    const float* We  = (const float*)d_in[16];
    const float* be  = (const float*)d_in[17];
    const float* ge  = (const float*)d_in[18];
    const float* bte = (const float*)d_in[19];
    const float* W1  = (const float*)d_in[20];
    const float* b1  = (const float*)d_in[21];
    const float* W2  = (const float*)d_in[22];
    const float* b2  = (const float*)d_in[23];

    float* ws        = (float*)d_ws;
    float* rel_repr  = ws;                       // B*RR*64 = 51200
    float* rel_agg   = ws + 51200;               // 51200
    float* rel_layer = ws + 102400;              // 51200
    float* query     = ws + 153600;              // 256
    float* x_ent     = ws + 153856;              // B*NN*64 = 5,120,000
    float* agg_ent   = x_ent + (size_t)B_ * NN * 64;

    int* iw          = (int*)(agg_ent + (size_t)B_ * NN * 64);
    int* ent_counts  = iw;                       // NN (becomes cursor)
    int* ent_rowptr  = iw + NN;                  // NN+1
    int* ent_packed  = iw + NN + NN + 1;         // EE
    int* rel_counts  = ent_packed + EE;          // RR (becomes cursor)
    int* rel_rowptr  = rel_counts + RR;          // RR+1
    int* rel_packed  = rel_rowptr + RR + 1;      // ER_

    // ---- CSR build (both graphs) ----
    k_zero_int<<<(NN + 255) / 256, 256, 0, stream>>>(ent_counts, NN);
    k_zero_int<<<1, 256, 0, stream>>>(rel_counts, RR);
    k_hist<<<(EE + 255) / 256, 256, 0, stream>>>(edge_index, EE, ent_counts);
    k_hist<<<(ER_ + 255) / 256, 256, 0, stream>>>(rel_ei, ER_, rel_counts);
    k_scan<<<1, 256, 0, stream>>>(ent_counts, ent_rowptr, NN);
    k_scan<<<1, 256, 0, stream>>>(rel_counts, rel_rowptr, RR);
    k_fill<<<(EE + 255) / 256, 256, 0, stream>>>(edge_index, edge_type, EE, ent_counts, ent_packed);
    k_fill<<<(ER_ + 255) / 256, 256, 0, stream>>>(rel_ei, rel_et, ER_, rel_counts, rel_packed);

    // ---- relation-graph model ----
    k_rel_init<<<(B_ * RR * 16 + 255) / 256, 256, 0, stream>>>(rel_repr, batch);
    for (int l = 0; l < L_; ++l) {
        k_agg_rel<<<(RR + 3) / 4, 256, 0, stream>>>(rel_repr, rel_emb, rel_rowptr,
                                                    rel_packed, batch, rel_agg);
        k_conv<RR><<<(B_ * RR + 63) / 64, 256, 0, stream>>>(
            rel_repr, rel_agg, Wr + l * 8192, br + l * 64, gr + l * 64, btr + l * 64);
    }

    // ---- entity-graph model ----
    k_query<<<1, 256, 0, stream>>>(rel_repr, batch, query);
    k_ent_init<<<B_ * NN * 16 / 256, 256, 0, stream>>>(x_ent, query, batch);
    for (int l = 0; l < L_; ++l) {
        k_rel_mlp<<<B_ * RR, 64, 0, stream>>>(rel_repr,
            Wp1 + l * 4096, bp1 + l * 64, Wp2 + l * 4096, bp2 + l * 64, rel_layer);
        k_agg_ent<<<(NN + 3) / 4, 256, 0, stream>>>(x_ent, rel_layer, ent_rowptr,
                                                    ent_packed, query, batch, agg_ent);
        k_conv<NN><<<(B_ * NN + 63) / 64, 256, 0, stream>>>(
            x_ent, agg_ent, We + l * 8192, be + l * 64, ge + l * 64, bte + l * 64);
    }
    k_final<<<B_ * K_, 128, 0, stream>>>(x_ent, query, batch, W1, b1, W2, b2,
                                         (float*)d_out);
}

// Round 4
// 576.018 us; speedup vs baseline: 8.1058x; 1.4312x over previous
//
#include <hip/hip_runtime.h>
#include <hip/hip_bf16.h>

#define D_   64
#define L_   6
#define B_   4
#define K_   256
#define NN   20000
#define EE   200000
#define RR   200
#define ER_  4000
#define EPS_ 1e-5f

// ================= CSR build (generic, run once per launch per graph) =======
__global__ __launch_bounds__(256)
void k_zero_int(int* __restrict__ p, int n) {
    int i = blockIdx.x * 256 + threadIdx.x;
    if (i < n) p[i] = 0;
}

__global__ __launch_bounds__(256)
void k_hist(const int* __restrict__ ei, int E, int* __restrict__ counts) {
    int e = blockIdx.x * 256 + threadIdx.x;
    if (e < E) atomicAdd(&counts[ei[E + e]], 1);
}

// single-block scan: row_ptr[0..n] = exclusive prefix of counts; counts becomes cursor copy
__global__ __launch_bounds__(256)
void k_scan(int* __restrict__ counts, int* __restrict__ row_ptr, int n) {
    __shared__ int sums[256];
    int tid = threadIdx.x;
    int chunk = (n + 255) / 256;
    int lo = tid * chunk;
    int hi = lo + chunk; if (hi > n) hi = n;
    if (lo > n) lo = n;
    int s = 0;
    for (int i = lo; i < hi; i++) s += counts[i];
    sums[tid] = s;
    __syncthreads();
    if (tid == 0) {
        int acc = 0;
        for (int i = 0; i < 256; i++) { int t = sums[i]; sums[i] = acc; acc += t; }
    }
    __syncthreads();
    int run = sums[tid];
    for (int i = lo; i < hi; i++) {
        int c = counts[i];
        row_ptr[i] = run;
        counts[i] = run;        // cursor init (reuse counts buffer)
        run += c;
    }
    if (hi == n) row_ptr[n] = run;   // trailing threads write total (same value)
}

__global__ __launch_bounds__(256)
void k_fill(const int* __restrict__ ei, const int* __restrict__ et, int E,
            int* __restrict__ cursor, int* __restrict__ packed) {
    int e = blockIdx.x * 256 + threadIdx.x;
    if (e < E) {
        int pos = atomicAdd(&cursor[ei[E + e]], 1);
        packed[pos] = ei[e] | (et[e] << 15);     // src < 32768, et < 200
    }
}

// ================= rel-graph init: x = boundary (1.0 at r_index row) ========
__global__ __launch_bounds__(256)
void k_rel_init(float* __restrict__ x, const int* __restrict__ batch) {
    int idx = blockIdx.x * 256 + threadIdx.x;              // over B*RR*16 float4
    int total = B_ * RR * (D_ / 4);
    if (idx >= total) return;
    int r = (idx >> 4) % RR;
    int b = (idx >> 4) / RR;
    int ridx = batch[b * K_ * 3 + 2];
    float4 v = make_float4(0.f, 0.f, 0.f, 0.f);
    if (r == ridx) v = make_float4(1.f, 1.f, 1.f, 1.f);
    reinterpret_cast<float4*>(x)[idx] = v;
}

// ================= CSR aggregation (rel graph, small) =======================
__global__ __launch_bounds__(256)
void k_agg_rel(const float* __restrict__ x, const float* __restrict__ rel_emb,
               const int* __restrict__ row_ptr, const int* __restrict__ packed,
               const int* __restrict__ batch, float* __restrict__ agg) {
    int node = blockIdx.x * 4 + (threadIdx.x >> 6);
    int d = threadIdx.x & 63;
    if (node >= RR) return;
    int beg = row_ptr[node], end = row_ptr[node + 1];
    float a0 = 0.f, a1 = 0.f, a2 = 0.f, a3 = 0.f;
    for (int e = beg; e < end; e++) {
        int p = packed[e];
        int src = p & 0x7FFF;
        int et  = p >> 15;
        float rv = rel_emb[et * 64 + d];
        a0 = fmaf(x[(0 * RR + src) * 64 + d], rv, a0);
        a1 = fmaf(x[(1 * RR + src) * 64 + d], rv, a1);
        a2 = fmaf(x[(2 * RR + src) * 64 + d], rv, a2);
        a3 = fmaf(x[(3 * RR + src) * 64 + d], rv, a3);
    }
    if (node == batch[0 * K_ * 3 + 2]) a0 += 1.f;
    if (node == batch[1 * K_ * 3 + 2]) a1 += 1.f;
    if (node == batch[2 * K_ * 3 + 2]) a2 += 1.f;
    if (node == batch[3 * K_ * 3 + 2]) a3 += 1.f;
    agg[(0 * RR + node) * 64 + d] = a0;
    agg[(1 * RR + node) * 64 + d] = a1;
    agg[(2 * RR + node) * 64 + d] = a2;
    agg[(3 * RR + node) * 64 + d] = a3;
}

// ================= CSR aggregation (ent graph): 4-edge chunked ==============
// wave = node; 4 subgroups of 16 lanes each take one edge; lane = float4 of dims
__global__ __launch_bounds__(256)
void k_agg_ent(const float* __restrict__ x, const float* __restrict__ rel,
               const int* __restrict__ row_ptr, const int* __restrict__ packed,
               const float* __restrict__ query, const int* __restrict__ batch,
               float* __restrict__ agg) {
    int node = blockIdx.x * 4 + (threadIdx.x >> 6);
    int lane = threadIdx.x & 63;
    int sub  = lane >> 4;        // edge slot 0..3
    int d4   = lane & 15;        // float4 index within row
    if (node >= NN) return;
    int beg = row_ptr[node], end = row_ptr[node + 1];

    const float4* x4 = reinterpret_cast<const float4*>(x);
    const float4* r4 = reinterpret_cast<const float4*>(rel);

    float4 a0 = make_float4(0.f,0.f,0.f,0.f), a1 = a0, a2 = a0, a3 = a0;

    for (int e0 = beg; e0 < end; e0 += 4) {
        int e = e0 + sub;
        if (e < end) {
            int p = packed[e];
            int src = p & 0x7FFF;
            int et  = p >> 15;
            {
                float4 xv = x4[((size_t)0 * NN + src) * 16 + d4];
                float4 rv = r4[(0 * RR + et) * 16 + d4];
                a0.x = fmaf(xv.x, rv.x, a0.x); a0.y = fmaf(xv.y, rv.y, a0.y);
                a0.z = fmaf(xv.z, rv.z, a0.z); a0.w = fmaf(xv.w, rv.w, a0.w);
            }
            {
                float4 xv = x4[((size_t)1 * NN + src) * 16 + d4];
                float4 rv = r4[(1 * RR + et) * 16 + d4];
                a1.x = fmaf(xv.x, rv.x, a1.x); a1.y = fmaf(xv.y, rv.y, a1.y);
                a1.z = fmaf(xv.z, rv.z, a1.z); a1.w = fmaf(xv.w, rv.w, a1.w);
            }
            {
                float4 xv = x4[((size_t)2 * NN + src) * 16 + d4];
                float4 rv = r4[(2 * RR + et) * 16 + d4];
                a2.x = fmaf(xv.x, rv.x, a2.x); a2.y = fmaf(xv.y, rv.y, a2.y);
                a2.z = fmaf(xv.z, rv.z, a2.z); a2.w = fmaf(xv.w, rv.w, a2.w);
            }
            {
                float4 xv = x4[((size_t)3 * NN + src) * 16 + d4];
                float4 rv = r4[(3 * RR + et) * 16 + d4];
                a3.x = fmaf(xv.x, rv.x, a3.x); a3.y = fmaf(xv.y, rv.y, a3.y);
                a3.z = fmaf(xv.z, rv.z, a3.z); a3.w = fmaf(xv.w, rv.w, a3.w);
            }
        }
    }

    // cross-subgroup reduce (lanes l, l+16, l+32, l+48 hold same dims)
    #define RED(v) v.x += __shfl_xor(v.x,16); v.y += __shfl_xor(v.y,16); \
                   v.z += __shfl_xor(v.z,16); v.w += __shfl_xor(v.w,16); \
                   v.x += __shfl_xor(v.x,32); v.y += __shfl_xor(v.y,32); \
                   v.z += __shfl_xor(v.z,32); v.w += __shfl_xor(v.w,32);
    RED(a0) RED(a1) RED(a2) RED(a3)
    #undef RED

    const float4* q4 = reinterpret_cast<const float4*>(query);
    float4* agg4 = reinterpret_cast<float4*>(agg);
    if (sub == 0) {
        if (node == batch[0 * K_ * 3]) {
            float4 q = q4[0 * 16 + d4];
            a0.x += q.x; a0.y += q.y; a0.z += q.z; a0.w += q.w;
        }
        agg4[((size_t)0 * NN + node) * 16 + d4] = a0;
    } else if (sub == 1) {
        if (node == batch[1 * K_ * 3]) {
            float4 q = q4[1 * 16 + d4];
            a1.x += q.x; a1.y += q.y; a1.z += q.z; a1.w += q.w;
        }
        agg4[((size_t)1 * NN + node) * 16 + d4] = a1;
    } else if (sub == 2) {
        if (node == batch[2 * K_ * 3]) {
            float4 q = q4[2 * 16 + d4];
            a2.x += q.x; a2.y += q.y; a2.z += q.z; a2.w += q.w;
        }
        agg4[((size_t)2 * NN + node) * 16 + d4] = a2;
    } else {
        if (node == batch[3 * K_ * 3]) {
            float4 q = q4[3 * 16 + d4];
            a3.x += q.x; a3.y += q.y; a3.z += q.z; a3.w += q.w;
        }
        agg4[((size_t)3 * NN + node) * 16 + d4] = a3;
    }
}

// ================= conv: split-K two-pass GEMM + LN + relu + residual =======
// out = relu(LN(x@W[0:64] + agg@W[64:128] + b)); x += out (residual)
template<int NNODES>
__global__ __launch_bounds__(256)
void k_conv(float* __restrict__ x, const float* __restrict__ agg,
            const float* __restrict__ W, const float* __restrict__ bias,
            const float* __restrict__ g, const float* __restrict__ bt) {
    __shared__ float As[64][68];   // row-major [m][k], pad 68 (conflict-free)
    __shared__ float Ws[64][64];   // W half tile [k][n]
    const int tid = threadIdx.x;
    const int row0 = blockIdx.x * 64;
    const int total_rows = B_ * NNODES;
    const int tx = tid & 15;       // output col group (4 cols)
    const int ty = tid >> 4;       // row group (4 rows)

    float acc[4][4];
    #pragma unroll
    for (int j = 0; j < 4; j++)
        #pragma unroll
        for (int i = 0; i < 4; i++) acc[j][i] = 0.f;
    float4 res[4];

    #pragma unroll
    for (int pass = 0; pass < 2; ++pass) {
        const float* src = pass ? agg : x;
        const float* Wp  = W + pass * 64 * 64;

        __syncthreads();   // previous pass readers done before overwrite
        // stage A tile (64 rows x 64 k) and W half (64 k x 64 n)
        for (int i = tid; i < 1024; i += 256) {
            int m = i >> 4, k0 = (i & 15) * 4;
            int row = row0 + m;
            float4 v = make_float4(0.f, 0.f, 0.f, 0.f);
            if (row < total_rows)
                v = *reinterpret_cast<const float4*>(src + (size_t)row * 64 + k0);
            *reinterpret_cast<float4*>(&As[m][k0]) = v;
            *reinterpret_cast<float4*>(&Ws[m][k0]) =
                *reinterpret_cast<const float4*>(Wp + m * 64 + k0);
        }
        __syncthreads();

        #pragma unroll 2
        for (int k = 0; k < 64; k += 4) {
            float4 a0 = *reinterpret_cast<const float4*>(&As[ty * 4 + 0][k]);
            float4 a1 = *reinterpret_cast<const float4*>(&As[ty * 4 + 1][k]);
            float4 a2 = *reinterpret_cast<const float4*>(&As[ty * 4 + 2][k]);
            float4 a3 = *reinterpret_cast<const float4*>(&As[ty * 4 + 3][k]);
            float4 w0 = *reinterpret_cast<const float4*>(&Ws[k + 0][tx * 4]);
            float4 w1 = *reinterpret_cast<const float4*>(&Ws[k + 1][tx * 4]);
            float4 w2 = *reinterpret_cast<const float4*>(&Ws[k + 2][tx * 4]);
            float4 w3 = *reinterpret_cast<const float4*>(&Ws[k + 3][tx * 4]);
            float am[4][4] = {{a0.x,a0.y,a0.z,a0.w},{a1.x,a1.y,a1.z,a1.w},
                              {a2.x,a2.y,a2.z,a2.w},{a3.x,a3.y,a3.z,a3.w}};
            float wm[4][4] = {{w0.x,w0.y,w0.z,w0.w},{w1.x,w1.y,w1.z,w1.w},
                              {w2.x,w2.y,w2.z,w2.w},{w3.x,w3.y,w3.z,w3.w}};
            #pragma unroll
            for (int kk = 0; kk < 4; kk++)
                #pragma unroll
                for (int j = 0; j < 4; j++)
                    #pragma unroll
                    for (int i = 0; i < 4; i++)
                        acc[j][i] = fmaf(am[j][kk], wm[kk][i], acc[j][i]);
        }

        if (pass == 0) {   // save x_old for residual before tile is overwritten
            #pragma unroll
            for (int j = 0; j < 4; j++)
                res[j] = *reinterpret_cast<const float4*>(&As[ty * 4 + j][tx * 4]);
        }
    }

    float bb[4], gg[4], bbt[4];
    #pragma unroll
    for (int i = 0; i < 4; i++) {
        bb[i]  = bias[tx * 4 + i];
        gg[i]  = g[tx * 4 + i];
        bbt[i] = bt[tx * 4 + i];
    }

    #pragma unroll
    for (int j = 0; j < 4; j++) {
        int row = row0 + ty * 4 + j;
        float o[4];
        float s1 = 0.f, s2 = 0.f;
        #pragma unroll
        for (int i = 0; i < 4; i++) {
            o[i] = acc[j][i] + bb[i];
            s1 += o[i];
            s2 += o[i] * o[i];
        }
        #pragma unroll
        for (int off = 1; off < 16; off <<= 1) {
            s1 += __shfl_xor(s1, off);
            s2 += __shfl_xor(s2, off);
        }
        float mean = s1 * (1.f / 64.f);
        float var  = s2 * (1.f / 64.f) - mean * mean;
        float inv  = rsqrtf(var + EPS_);
        if (row < total_rows) {
            float rj[4] = {res[j].x, res[j].y, res[j].z, res[j].w};
            float nv[4];
            #pragma unroll
            for (int i = 0; i < 4; i++) {
                float h = (o[i] - mean) * inv * gg[i] + bbt[i];
                h = fmaxf(h, 0.f);
                nv[i] = rj[i] + h;
            }
            *reinterpret_cast<float4*>(&x[(size_t)row * 64 + tx * 4]) =
                make_float4(nv[0], nv[1], nv[2], nv[3]);
        }
    }
}

// ================= per-layer relation MLP ==================================
__global__ __launch_bounds__(64)
void k_rel_mlp(const float* __restrict__ rel_repr,
               const float* __restrict__ Wp1, const float* __restrict__ bp1,
               const float* __restrict__ Wp2, const float* __restrict__ bp2,
               float* __restrict__ out) {
    __shared__ float rowv[64];
    __shared__ float hid[64];
    int rowid = blockIdx.x;
    int d = threadIdx.x;
    rowv[d] = rel_repr[rowid * 64 + d];
    __syncthreads();
    float acc = bp1[d];
    for (int k = 0; k < 64; k++) acc = fmaf(rowv[k], Wp1[k * 64 + d], acc);
    hid[d] = fmaxf(acc, 0.f);
    __syncthreads();
    float o = bp2[d];
    for (int k = 0; k < 64; k++) o = fmaf(hid[k], Wp2[k * 64 + d], o);
    out[rowid * 64 + d] = o;
}

// ================= query[b] = rel_repr[b, r_index[b]] ======================
__global__ __launch_bounds__(256)
void k_query(const float* __restrict__ rel_repr, const int* __restrict__ batch,
             float* __restrict__ query) {
    int tid = threadIdx.x;  // 256 = B*64
    int b = tid >> 6;
    int d = tid & 63;
    int r = batch[b * K_ * 3 + 2];
    query[b * 64 + d] = rel_repr[(b * RR + r) * 64 + d];
}

// ================= ent init: x = boundary (query at h_index row) ===========
__global__ __launch_bounds__(256)
void k_ent_init(float* __restrict__ x, const float* __restrict__ query,
                const int* __restrict__ batch) {
    int idx = blockIdx.x * 256 + threadIdx.x;  // over B*NN*16 float4
    int total = B_ * NN * (D_ / 4);
    if (idx >= total) return;
    int d4 = idx & 15;
    int rest = idx >> 4;
    int n = rest % NN;
    int b = rest / NN;
    int h = batch[b * K_ * 3];
    float4 v = make_float4(0.f, 0.f, 0.f, 0.f);
    if (n == h) v = reinterpret_cast<const float4*>(query)[b * 16 + d4];
    reinterpret_cast<float4*>(x)[idx] = v;
}

// ================= final MLP over gathered rows ============================
__global__ __launch_bounds__(128)
void k_final(const float* __restrict__ x, const float* __restrict__ query,
             const int* __restrict__ batch,
             const float* __restrict__ W1, const float* __restrict__ b1,
             const float* __restrict__ W2, const float* __restrict__ b2,
             float* __restrict__ out) {
    __shared__ float feat[128];
    __shared__ float partial[2];
    int pair = blockIdx.x;          // b*K + k
    int b = pair / K_;
    int t = batch[pair * 3 + 1];
    int d = threadIdx.x;
    feat[d] = (d < 64) ? x[(size_t)(b * NN + t) * 64 + d] : query[b * 64 + (d - 64)];
    __syncthreads();
    float h = b1[d];
    for (int i = 0; i < 128; i++) h = fmaf(feat[i], W1[i * 128 + d], h);
    h = fmaxf(h, 0.f);
    float v = h * W2[d];
    #pragma unroll
    for (int off = 1; off < 64; off <<= 1) v += __shfl_xor(v, off);
    if ((d & 63) == 0) partial[d >> 6] = v;
    __syncthreads();
    if (d == 0) out[pair] = partial[0] + partial[1] + b2[0];
}

extern "C" void kernel_launch(void* const* d_in, const int* in_sizes, int n_in,
                              void* d_out, int out_size, void* d_ws, size_t ws_size,
                              hipStream_t stream) {
    const int* batch      = (const int*)d_in[0];
    const int* edge_index = (const int*)d_in[1];
    const int* edge_type  = (const int*)d_in[2];
    const int* rel_ei     = (const int*)d_in[3];
    const int* rel_et     = (const int*)d_in[4];
    const float* rel_emb = (const float*)d_in[7];
    const float* Wr  = (const float*)d_in[8];
    const float* br  = (const float*)d_in[9];
    const float* gr  = (const float*)d_in[10];
    const float* btr = (const float*)d_in[11];
    const float* Wp1 = (const float*)d_in[12];
    const float* bp1 = (const float*)d_in[13];
    const float* Wp2 = (const float*)d_in[14];
    const float* bp2 = (const float*)d_in[15];
    const float* We  = (const float*)d_in[16];
    const float* be  = (const float*)d_in[17];
    const float* ge  = (const float*)d_in[18];
    const float* bte = (const float*)d_in[19];
    const float* W1  = (const float*)d_in[20];
    const float* b1  = (const float*)d_in[21];
    const float* W2  = (const float*)d_in[22];
    const float* b2  = (const float*)d_in[23];

    float* ws        = (float*)d_ws;
    float* rel_repr  = ws;                       // B*RR*64 = 51200
    float* rel_agg   = ws + 51200;               // 51200
    float* rel_layer = ws + 102400;              // 51200
    float* query     = ws + 153600;               // 256
    float* x_ent     = ws + 153856;              // B*NN*64 = 5,120,000
    float* agg_ent   = x_ent + (size_t)B_ * NN * 64;

    int* iw          = (int*)(agg_ent + (size_t)B_ * NN * 64);
    int* ent_counts  = iw;                       // NN (becomes cursor)
    int* ent_rowptr  = iw + NN;                  // NN+1
    int* ent_packed  = iw + NN + NN + 1;         // EE
    int* rel_counts  = ent_packed + EE;          // RR (becomes cursor)
    int* rel_rowptr  = rel_counts + RR;          // RR+1
    int* rel_packed  = rel_rowptr + RR + 1;      // ER_

    // ---- CSR build (both graphs) ----
    k_zero_int<<<(NN + 255) / 256, 256, 0, stream>>>(ent_counts, NN);
    k_zero_int<<<1, 256, 0, stream>>>(rel_counts, RR);
    k_hist<<<(EE + 255) / 256, 256, 0, stream>>>(edge_index, EE, ent_counts);
    k_hist<<<(ER_ + 255) / 256, 256, 0, stream>>>(rel_ei, ER_, rel_counts);
    k_scan<<<1, 256, 0, stream>>>(ent_counts, ent_rowptr, NN);
    k_scan<<<1, 256, 0, stream>>>(rel_counts, rel_rowptr, RR);
    k_fill<<<(EE + 255) / 256, 256, 0, stream>>>(edge_index, edge_type, EE, ent_counts, ent_packed);
    k_fill<<<(ER_ + 255) / 256, 256, 0, stream>>>(rel_ei, rel_et, ER_, rel_counts, rel_packed);

    // ---- relation-graph model ----
    k_rel_init<<<(B_ * RR * 16 + 255) / 256, 256, 0, stream>>>(rel_repr, batch);
    for (int l = 0; l < L_; ++l) {
        k_agg_rel<<<(RR + 3) / 4, 256, 0, stream>>>(rel_repr, rel_emb, rel_rowptr,
                                                    rel_packed, batch, rel_agg);
        k_conv<RR><<<(B_ * RR + 63) / 64, 256, 0, stream>>>(
            rel_repr, rel_agg, Wr + l * 8192, br + l * 64, gr + l * 64, btr + l * 64);
    }

    // ---- entity-graph model ----
    k_query<<<1, 256, 0, stream>>>(rel_repr, batch, query);
    k_ent_init<<<B_ * NN * 16 / 256, 256, 0, stream>>>(x_ent, query, batch);
    for (int l = 0; l < L_; ++l) {
        k_rel_mlp<<<B_ * RR, 64, 0, stream>>>(rel_repr,
            Wp1 + l * 4096, bp1 + l * 64, Wp2 + l * 4096, bp2 + l * 64, rel_layer);
        k_agg_ent<<<(NN + 3) / 4, 256, 0, stream>>>(x_ent, rel_layer, ent_rowptr,
                                                    ent_packed, query, batch, agg_ent);
        k_conv<NN><<<(B_ * NN + 63) / 64, 256, 0, stream>>>(
            x_ent, agg_ent, We + l * 8192, be + l * 64, ge + l * 64, bte + l * 64);
    }
    k_final<<<B_ * K_, 128, 0, stream>>>(x_ent, query, batch, W1, b1, W2, b2,
                                         (float*)d_out);
}

// Round 5
// 562.564 us; speedup vs baseline: 8.2996x; 1.0239x over previous
//
#include <hip/hip_runtime.h>
#include <hip/hip_bf16.h>

#define D_   64
#define L_   6
#define B_   4
#define K_   256
#define NN   20000
#define EE   200000
#define RR   200
#define ER_  4000
#define EPS_ 1e-5f

typedef unsigned short u16;
typedef unsigned int   u32;

__device__ __forceinline__ u16 f2bf(float f) {          // RNE f32 -> bf16
    u32 u = __float_as_uint(f);
    u += 0x7FFF + ((u >> 16) & 1);
    return (u16)(u >> 16);
}
__device__ __forceinline__ float bflo(u32 u) { return __uint_as_float(u << 16); }
__device__ __forceinline__ float bfhi(u32 u) { return __uint_as_float(u & 0xFFFF0000u); }

// ================= CSR build =================
__global__ __launch_bounds__(256)
void k_zero_int(int* __restrict__ p, int n) {
    int i = blockIdx.x * 256 + threadIdx.x;
    if (i < n) p[i] = 0;
}

__global__ __launch_bounds__(256)
void k_hist(const int* __restrict__ ei, int E, int* __restrict__ counts) {
    int e = blockIdx.x * 256 + threadIdx.x;
    if (e < E) atomicAdd(&counts[ei[E + e]], 1);
}

// block-local exclusive scan over 1024 counts per block; bsums[blk] = block total
__global__ __launch_bounds__(256)
void k_scan1(const int* __restrict__ counts, int n, int* __restrict__ pre,
             int* __restrict__ bsums) {
    __shared__ int tsum[256];
    int tid = threadIdx.x;
    int base = blockIdx.x * 1024 + tid * 4;
    int c0 = 0, c1 = 0, c2 = 0, c3 = 0;
    if (base + 0 < n) c0 = counts[base + 0];
    if (base + 1 < n) c1 = counts[base + 1];
    if (base + 2 < n) c2 = counts[base + 2];
    if (base + 3 < n) c3 = counts[base + 3];
    tsum[tid] = c0 + c1 + c2 + c3;
    __syncthreads();
    if (tid == 0) {
        int acc = 0;
        for (int i = 0; i < 256; i++) { int t = tsum[i]; tsum[i] = acc; acc += t; }
    }
    __syncthreads();
    int run = tsum[tid];
    if (base + 0 < n) pre[base + 0] = run; run += c0;
    if (base + 1 < n) pre[base + 1] = run; run += c1;
    if (base + 2 < n) pre[base + 2] = run; run += c2;
    if (base + 3 < n) pre[base + 3] = run; run += c3;
    if (tid == 255) bsums[blockIdx.x] = run;
}

// scan the (few) block sums; write grand total to row_ptr[n]
__global__ __launch_bounds__(64)
void k_scan2(int* __restrict__ bsums, int nb, int* __restrict__ total_out) {
    if (threadIdx.x == 0) {
        int acc = 0;
        for (int i = 0; i < nb; i++) { int t = bsums[i]; bsums[i] = acc; acc += t; }
        *total_out = acc;
    }
}

// add block offsets; also init cursor
__global__ __launch_bounds__(256)
void k_scan3(int* __restrict__ row_ptr, const int* __restrict__ bsums, int n,
             int* __restrict__ cursor) {
    int i = blockIdx.x * 256 + threadIdx.x;
    if (i < n) {
        int v = row_ptr[i] + bsums[i >> 10];
        row_ptr[i] = v;
        cursor[i] = v;
    }
}

__global__ __launch_bounds__(256)
void k_fill(const int* __restrict__ ei, const int* __restrict__ et, int E,
            int* __restrict__ cursor, int* __restrict__ packed) {
    int e = blockIdx.x * 256 + threadIdx.x;
    if (e < E) {
        int pos = atomicAdd(&cursor[ei[E + e]], 1);
        packed[pos] = ei[e] | (et[e] << 15);     // src < 32768, et < 200
    }
}

// ================= rel-graph init ================
__global__ __launch_bounds__(256)
void k_rel_init(float* __restrict__ x, const int* __restrict__ batch) {
    int idx = blockIdx.x * 256 + threadIdx.x;              // over B*RR*16 float4
    int total = B_ * RR * (D_ / 4);
    if (idx >= total) return;
    int r = (idx >> 4) % RR;
    int b = (idx >> 4) / RR;
    int ridx = batch[b * K_ * 3 + 2];
    float4 v = make_float4(0.f, 0.f, 0.f, 0.f);
    if (r == ridx) v = make_float4(1.f, 1.f, 1.f, 1.f);
    reinterpret_cast<float4*>(x)[idx] = v;
}

// ================= rel-graph aggregation (small, f32) ================
__global__ __launch_bounds__(256)
void k_agg_rel(const float* __restrict__ x, const float* __restrict__ rel_emb,
               const int* __restrict__ row_ptr, const int* __restrict__ packed,
               const int* __restrict__ batch, float* __restrict__ agg) {
    int node = blockIdx.x * 4 + (threadIdx.x >> 6);
    int d = threadIdx.x & 63;
    if (node >= RR) return;
    int beg = row_ptr[node], end = row_ptr[node + 1];
    float a0 = 0.f, a1 = 0.f, a2 = 0.f, a3 = 0.f;
    for (int e = beg; e < end; e++) {
        int p = packed[e];
        int src = p & 0x7FFF;
        int et  = p >> 15;
        float rv = rel_emb[et * 64 + d];
        a0 = fmaf(x[(0 * RR + src) * 64 + d], rv, a0);
        a1 = fmaf(x[(1 * RR + src) * 64 + d], rv, a1);
        a2 = fmaf(x[(2 * RR + src) * 64 + d], rv, a2);
        a3 = fmaf(x[(3 * RR + src) * 64 + d], rv, a3);
    }
    if (node == batch[0 * K_ * 3 + 2]) a0 += 1.f;
    if (node == batch[1 * K_ * 3 + 2]) a1 += 1.f;
    if (node == batch[2 * K_ * 3 + 2]) a2 += 1.f;
    if (node == batch[3 * K_ * 3 + 2]) a3 += 1.f;
    agg[(0 * RR + node) * 64 + d] = a0;
    agg[(1 * RR + node) * 64 + d] = a1;
    agg[(2 * RR + node) * 64 + d] = a2;
    agg[(3 * RR + node) * 64 + d] = a3;
}

// ================= ent-graph aggregation: bf16 gather, 8-edge chunked =======
// wave = node; 8 subgroups of 8 lanes each take one edge; lane = 8 dims (16B)
__global__ __launch_bounds__(256)
void k_agg_ent(const u16* __restrict__ xb, const u16* __restrict__ relb,
               const int* __restrict__ row_ptr, const int* __restrict__ packed,
               const float* __restrict__ query, const int* __restrict__ batch,
               float* __restrict__ agg) {
    int node = blockIdx.x * 4 + (threadIdx.x >> 6);
    int lane = threadIdx.x & 63;
    int slot = lane >> 3;        // edge slot 0..7
    int d8   = lane & 7;         // dim block (8 dims)
    if (node >= NN) return;
    int beg = row_ptr[node], end = row_ptr[node + 1];

    float acc[4][8];
    #pragma unroll
    for (int b = 0; b < 4; b++)
        #pragma unroll
        for (int i = 0; i < 8; i++) acc[b][i] = 0.f;

    for (int e0 = beg; e0 < end; e0 += 8) {
        int e = e0 + slot;
        if (e < end) {
            int p = packed[e];
            int src = p & 0x7FFF;
            int et  = p >> 15;
            #pragma unroll
            for (int b = 0; b < 4; b++) {
                uint4 xv = *reinterpret_cast<const uint4*>(xb + ((size_t)b * NN + src) * 64 + d8 * 8);
                uint4 rv = *reinterpret_cast<const uint4*>(relb + (b * RR + et) * 64 + d8 * 8);
                acc[b][0] = fmaf(bflo(xv.x), bflo(rv.x), acc[b][0]);
                acc[b][1] = fmaf(bfhi(xv.x), bfhi(rv.x), acc[b][1]);
                acc[b][2] = fmaf(bflo(xv.y), bflo(rv.y), acc[b][2]);
                acc[b][3] = fmaf(bfhi(xv.y), bfhi(rv.y), acc[b][3]);
                acc[b][4] = fmaf(bflo(xv.z), bflo(rv.z), acc[b][4]);
                acc[b][5] = fmaf(bfhi(xv.z), bfhi(rv.z), acc[b][5]);
                acc[b][6] = fmaf(bflo(xv.w), bflo(rv.w), acc[b][6]);
                acc[b][7] = fmaf(bfhi(xv.w), bfhi(rv.w), acc[b][7]);
            }
        }
    }

    // reduce across the 8 slots (lanes sharing d8): xor 8,16,32
    #pragma unroll
    for (int b = 0; b < 4; b++)
        #pragma unroll
        for (int i = 0; i < 8; i++) {
            float v = acc[b][i];
            v += __shfl_xor(v, 8);
            v += __shfl_xor(v, 16);
            v += __shfl_xor(v, 32);
            acc[b][i] = v;
        }

    if (slot < 4) {
        int b = slot;
        float out[8];
        #pragma unroll
        for (int i = 0; i < 8; i++) out[i] = acc[b][i];
        if (node == batch[b * K_ * 3]) {
            #pragma unroll
            for (int i = 0; i < 8; i++) out[i] += query[b * 64 + d8 * 8 + i];
        }
        float4* dst = reinterpret_cast<float4*>(agg + ((size_t)b * NN + node) * 64 + d8 * 8);
        dst[0] = make_float4(out[0], out[1], out[2], out[3]);
        dst[1] = make_float4(out[4], out[5], out[6], out[7]);
    }
}

// ================= conv: split-K two-pass GEMM + LN + relu + residual =======
// out = relu(LN(x@W[0:64] + agg@W[64:128] + b)); x += out; optionally mirror to bf16
template<int NNODES>
__global__ __launch_bounds__(256)
void k_conv(float* __restrict__ x, const float* __restrict__ agg,
            const float* __restrict__ W, const float* __restrict__ bias,
            const float* __restrict__ g, const float* __restrict__ bt,
            u16* __restrict__ xb) {
    __shared__ float As[64][68];   // row-major [m][k], pad 68 (conflict-free)
    __shared__ float Ws[64][64];   // W half tile [k][n]
    const int tid = threadIdx.x;
    const int row0 = blockIdx.x * 64;
    const int total_rows = B_ * NNODES;
    const int tx = tid & 15;       // output col group (4 cols)
    const int ty = tid >> 4;       // row group (4 rows)

    float acc[4][4];
    #pragma unroll
    for (int j = 0; j < 4; j++)
        #pragma unroll
        for (int i = 0; i < 4; i++) acc[j][i] = 0.f;
    float4 res[4];

    #pragma unroll
    for (int pass = 0; pass < 2; ++pass) {
        const float* src = pass ? agg : x;
        const float* Wp  = W + pass * 64 * 64;

        __syncthreads();   // previous pass readers done before overwrite
        for (int i = tid; i < 1024; i += 256) {
            int m = i >> 4, k0 = (i & 15) * 4;
            int row = row0 + m;
            float4 v = make_float4(0.f, 0.f, 0.f, 0.f);
            if (row < total_rows)
                v = *reinterpret_cast<const float4*>(src + (size_t)row * 64 + k0);
            *reinterpret_cast<float4*>(&As[m][k0]) = v;
            *reinterpret_cast<float4*>(&Ws[m][k0]) =
                *reinterpret_cast<const float4*>(Wp + m * 64 + k0);
        }
        __syncthreads();

        #pragma unroll 2
        for (int k = 0; k < 64; k += 4) {
            float4 a0 = *reinterpret_cast<const float4*>(&As[ty * 4 + 0][k]);
            float4 a1 = *reinterpret_cast<const float4*>(&As[ty * 4 + 1][k]);
            float4 a2 = *reinterpret_cast<const float4*>(&As[ty * 4 + 2][k]);
            float4 a3 = *reinterpret_cast<const float4*>(&As[ty * 4 + 3][k]);
            float4 w0 = *reinterpret_cast<const float4*>(&Ws[k + 0][tx * 4]);
            float4 w1 = *reinterpret_cast<const float4*>(&Ws[k + 1][tx * 4]);
            float4 w2 = *reinterpret_cast<const float4*>(&Ws[k + 2][tx * 4]);
            float4 w3 = *reinterpret_cast<const float4*>(&Ws[k + 3][tx * 4]);
            float am[4][4] = {{a0.x,a0.y,a0.z,a0.w},{a1.x,a1.y,a1.z,a1.w},
                              {a2.x,a2.y,a2.z,a2.w},{a3.x,a3.y,a3.z,a3.w}};
            float wm[4][4] = {{w0.x,w0.y,w0.z,w0.w},{w1.x,w1.y,w1.z,w1.w},
                              {w2.x,w2.y,w2.z,w2.w},{w3.x,w3.y,w3.z,w3.w}};
            #pragma unroll
            for (int kk = 0; kk < 4; kk++)
                #pragma unroll
                for (int j = 0; j < 4; j++)
                    #pragma unroll
                    for (int i = 0; i < 4; i++)
                        acc[j][i] = fmaf(am[j][kk], wm[kk][i], acc[j][i]);
        }

        if (pass == 0) {   // save x_old for residual before tile is overwritten
            #pragma unroll
            for (int j = 0; j < 4; j++)
                res[j] = *reinterpret_cast<const float4*>(&As[ty * 4 + j][tx * 4]);
        }
    }

    float bb[4], gg[4], bbt[4];
    #pragma unroll
    for (int i = 0; i < 4; i++) {
        bb[i]  = bias[tx * 4 + i];
        gg[i]  = g[tx * 4 + i];
        bbt[i] = bt[tx * 4 + i];
    }

    #pragma unroll
    for (int j = 0; j < 4; j++) {
        int row = row0 + ty * 4 + j;
        float o[4];
        float s1 = 0.f, s2 = 0.f;
        #pragma unroll
        for (int i = 0; i < 4; i++) {
            o[i] = acc[j][i] + bb[i];
            s1 += o[i];
            s2 += o[i] * o[i];
        }
        #pragma unroll
        for (int off = 1; off < 16; off <<= 1) {
            s1 += __shfl_xor(s1, off);
            s2 += __shfl_xor(s2, off);
        }
        float mean = s1 * (1.f / 64.f);
        float var  = s2 * (1.f / 64.f) - mean * mean;
        float inv  = rsqrtf(var + EPS_);
        if (row < total_rows) {
            float rj[4] = {res[j].x, res[j].y, res[j].z, res[j].w};
            float nv[4];
            #pragma unroll
            for (int i = 0; i < 4; i++) {
                float h = (o[i] - mean) * inv * gg[i] + bbt[i];
                h = fmaxf(h, 0.f);
                nv[i] = rj[i] + h;
            }
            *reinterpret_cast<float4*>(&x[(size_t)row * 64 + tx * 4]) =
                make_float4(nv[0], nv[1], nv[2], nv[3]);
            if (xb) {
                ushort4 b4;
                b4.x = f2bf(nv[0]); b4.y = f2bf(nv[1]);
                b4.z = f2bf(nv[2]); b4.w = f2bf(nv[3]);
                *reinterpret_cast<ushort4*>(&xb[(size_t)row * 64 + tx * 4]) = b4;
            }
        }
    }
}

// ========== all-layer relation MLP: rel_all[l] = relu(rel_repr@Wp1+b)@Wp2+b (bf16 out)
__global__ __launch_bounds__(64)
void k_rel_mlp_all(const float* __restrict__ rel_repr,
                   const float* __restrict__ Wp1, const float* __restrict__ bp1,
                   const float* __restrict__ Wp2, const float* __restrict__ bp2,
                   u16* __restrict__ out) {
    __shared__ float rowv[64];
    __shared__ float hid[64];
    int l     = blockIdx.x / (B_ * RR);
    int rowid = blockIdx.x % (B_ * RR);
    int d = threadIdx.x;
    const float* w1 = Wp1 + l * 4096;
    const float* w2 = Wp2 + l * 4096;
    rowv[d] = rel_repr[rowid * 64 + d];
    __syncthreads();
    float acc = bp1[l * 64 + d];
    for (int k = 0; k < 64; k++) acc = fmaf(rowv[k], w1[k * 64 + d], acc);
    hid[d] = fmaxf(acc, 0.f);
    __syncthreads();
    float o = bp2[l * 64 + d];
    for (int k = 0; k < 64; k++) o = fmaf(hid[k], w2[k * 64 + d], o);
    out[(size_t)l * B_ * RR * 64 + rowid * 64 + d] = f2bf(o);
}

// ================= query[b] = rel_repr[b, r_index[b]] ======================
__global__ __launch_bounds__(256)
void k_query(const float* __restrict__ rel_repr, const int* __restrict__ batch,
             float* __restrict__ query) {
    int tid = threadIdx.x;  // 256 = B*64
    int b = tid >> 6;
    int d = tid & 63;
    int r = batch[b * K_ * 3 + 2];
    query[b * 64 + d] = rel_repr[(b * RR + r) * 64 + d];
}

// ================= ent init: x = boundary (query at h_index row) ===========
__global__ __launch_bounds__(256)
void k_ent_init(float* __restrict__ x, u16* __restrict__ xb,
                const float* __restrict__ query, const int* __restrict__ batch) {
    int idx = blockIdx.x * 256 + threadIdx.x;  // over B*NN*16 float4
    int total = B_ * NN * (D_ / 4);
    if (idx >= total) return;
    int d4 = idx & 15;
    int rest = idx >> 4;
    int n = rest % NN;
    int b = rest / NN;
    int h = batch[b * K_ * 3];
    float4 v = make_float4(0.f, 0.f, 0.f, 0.f);
    if (n == h) v = reinterpret_cast<const float4*>(query)[b * 16 + d4];
    reinterpret_cast<float4*>(x)[idx] = v;
    ushort4 b4;
    b4.x = f2bf(v.x); b4.y = f2bf(v.y); b4.z = f2bf(v.z); b4.w = f2bf(v.w);
    reinterpret_cast<ushort4*>(xb)[idx] = b4;
}

// ================= final MLP over gathered rows ============================
__global__ __launch_bounds__(128)
void k_final(const float* __restrict__ x, const float* __restrict__ query,
             const int* __restrict__ batch,
             const float* __restrict__ W1, const float* __restrict__ b1,
             const float* __restrict__ W2, const float* __restrict__ b2,
             float* __restrict__ out) {
    __shared__ float feat[128];
    __shared__ float partial[2];
    int pair = blockIdx.x;          // b*K + k
    int b = pair / K_;
    int t = batch[pair * 3 + 1];
    int d = threadIdx.x;
    feat[d] = (d < 64) ? x[(size_t)(b * NN + t) * 64 + d] : query[b * 64 + (d - 64)];
    __syncthreads();
    float h = b1[d];
    for (int i = 0; i < 128; i++) h = fmaf(feat[i], W1[i * 128 + d], h);
    h = fmaxf(h, 0.f);
    float v = h * W2[d];
    #pragma unroll
    for (int off = 1; off < 64; off <<= 1) v += __shfl_xor(v, off);
    if ((d & 63) == 0) partial[d >> 6] = v;
    __syncthreads();
    if (d == 0) out[pair] = partial[0] + partial[1] + b2[0];
}

extern "C" void kernel_launch(void* const* d_in, const int* in_sizes, int n_in,
                              void* d_out, int out_size, void* d_ws, size_t ws_size,
                              hipStream_t stream) {
    const int* batch      = (const int*)d_in[0];
    const int* edge_index = (const int*)d_in[1];
    const int* edge_type  = (const int*)d_in[2];
    const int* rel_ei     = (const int*)d_in[3];
    const int* rel_et     = (const int*)d_in[4];
    const float* rel_emb = (const float*)d_in[7];
    const float* Wr  = (const float*)d_in[8];
    const float* br  = (const float*)d_in[9];
    const float* gr  = (const float*)d_in[10];
    const float* btr = (const float*)d_in[11];
    const float* Wp1 = (const float*)d_in[12];
    const float* bp1 = (const float*)d_in[13];
    const float* Wp2 = (const float*)d_in[14];
    const float* bp2 = (const float*)d_in[15];
    const float* We  = (const float*)d_in[16];
    const float* be  = (const float*)d_in[17];
    const float* ge  = (const float*)d_in[18];
    const float* bte = (const float*)d_in[19];
    const float* W1  = (const float*)d_in[20];
    const float* b1  = (const float*)d_in[21];
    const float* W2  = (const float*)d_in[22];
    const float* b2  = (const float*)d_in[23];

    float* ws        = (float*)d_ws;
    float* rel_repr  = ws;                        // 51200
    float* rel_agg   = ws + 51200;                // 51200
    float* query     = ws + 102400;               // 256
    float* x_ent     = ws + 102656;               // 5,120,000
    float* agg_ent   = x_ent + (size_t)B_ * NN * 64;   // 5,120,000
    u16*   x_bf16    = (u16*)(agg_ent + (size_t)B_ * NN * 64);   // 5,120,000 u16
    u16*   rel_all   = x_bf16 + (size_t)B_ * NN * 64;            // 6*4*200*64 u16
    int*   iw        = (int*)(rel_all + (size_t)L_ * B_ * RR * 64);

    int* ent_counts  = iw;                        // NN (becomes cursor)
    int* ent_rowptr  = ent_counts + NN;           // NN+1
    int* ent_bsums   = ent_rowptr + NN + 1;       // 32
    int* ent_packed  = ent_bsums + 32;            // EE
    int* rel_counts  = ent_packed + EE;           // RR (becomes cursor)
    int* rel_rowptr  = rel_counts + RR;           // RR+1
    int* rel_bsums   = rel_rowptr + RR + 1;       // 8
    int* rel_packed  = rel_bsums + 8;             // ER_

    const int ENT_NB = (NN + 1023) / 1024;        // 20
    const int REL_NB = (RR + 1023) / 1024;        // 1

    // ---- CSR build (both graphs) ----
    k_zero_int<<<(NN + 255) / 256, 256, 0, stream>>>(ent_counts, NN);
    k_zero_int<<<1, 256, 0, stream>>>(rel_counts, RR);
    k_hist<<<(EE + 255) / 256, 256, 0, stream>>>(edge_index, EE, ent_counts);
    k_hist<<<(ER_ + 255) / 256, 256, 0, stream>>>(rel_ei, ER_, rel_counts);
    k_scan1<<<ENT_NB, 256, 0, stream>>>(ent_counts, NN, ent_rowptr, ent_bsums);
    k_scan1<<<REL_NB, 256, 0, stream>>>(rel_counts, RR, rel_rowptr, rel_bsums);
    k_scan2<<<1, 64, 0, stream>>>(ent_bsums, ENT_NB, ent_rowptr + NN);
    k_scan2<<<1, 64, 0, stream>>>(rel_bsums, REL_NB, rel_rowptr + RR);
    k_scan3<<<(NN + 255) / 256, 256, 0, stream>>>(ent_rowptr, ent_bsums, NN, ent_counts);
    k_scan3<<<(RR + 255) / 256, 256, 0, stream>>>(rel_rowptr, rel_bsums, RR, rel_counts);
    k_fill<<<(EE + 255) / 256, 256, 0, stream>>>(edge_index, edge_type, EE, ent_counts, ent_packed);
    k_fill<<<(ER_ + 255) / 256, 256, 0, stream>>>(rel_ei, rel_et, ER_, rel_counts, rel_packed);

    // ---- relation-graph model ----
    k_rel_init<<<(B_ * RR * 16 + 255) / 256, 256, 0, stream>>>(rel_repr, batch);
    for (int l = 0; l < L_; ++l) {
        k_agg_rel<<<(RR + 3) / 4, 256, 0, stream>>>(rel_repr, rel_emb, rel_rowptr,
                                                    rel_packed, batch, rel_agg);
        k_conv<RR><<<(B_ * RR + 63) / 64, 256, 0, stream>>>(
            rel_repr, rel_agg, Wr + l * 8192, br + l * 64, gr + l * 64, btr + l * 64,
            (u16*)nullptr);
    }

    // ---- entity-graph model ----
    k_query<<<1, 256, 0, stream>>>(rel_repr, batch, query);
    k_rel_mlp_all<<<L_ * B_ * RR, 64, 0, stream>>>(rel_repr, Wp1, bp1, Wp2, bp2, rel_all);
    k_ent_init<<<B_ * NN * 16 / 256, 256, 0, stream>>>(x_ent, x_bf16, query, batch);
    for (int l = 0; l < L_; ++l) {
        k_agg_ent<<<(NN + 3) / 4, 256, 0, stream>>>(x_bf16, rel_all + (size_t)l * B_ * RR * 64,
                                                    ent_rowptr, ent_packed, query, batch, agg_ent);
        k_conv<NN><<<(B_ * NN + 63) / 64, 256, 0, stream>>>(
            x_ent, agg_ent, We + l * 8192, be + l * 64, ge + l * 64, bte + l * 64, x_bf16);
    }
    k_final<<<B_ * K_, 128, 0, stream>>>(x_ent, query, batch, W1, b1, W2, b2,
                                         (float*)d_out);
}